// Round 3
// baseline (4463.399 us; speedup 1.0000x reference)
//
#include <hip/hip_runtime.h>
#include <cstdint>

// Problem constants
constexpr int NB = 8192;   // batch rows
constexpr int Dd = 1024;   // feature dim
constexpr int Hh = 4096;   // hidden
constexpr int Kc = 4096;   // codebook size

using ull = unsigned long long;
typedef _Float16 half8 __attribute__((ext_vector_type(8)));
typedef float floatx16 __attribute__((ext_vector_type(16)));

#define TPB 256

__device__ __forceinline__ float fourier1(int col, float v) {
    // even feature index -> sin, odd -> cos
    return (col & 1) ? __cosf(v) : __sinf(v);
}

// async global->LDS, 16B per lane (global_load_lds_dwordx4)
#define ASYNC_CP16(gp, sp)                                                          \
    __builtin_amdgcn_global_load_lds(                                               \
        (const __attribute__((address_space(1))) unsigned int*)(gp),                \
        (__attribute__((address_space(3))) unsigned int*)(sp), 16, 0, 0)

// ===========================================================================
// Split-fp16 MFMA GEMM:  C = (A @ B^T) * invscale + bias, fused epilogue.
// A: [M][Kd] as hi/lo fp16 planes; B: [N][Kd] hi/lo planes.
// Block tile 128(M) x 128(N), BK=32, 256 threads = 4 waves (2x2), wave tile
// 64x64 = 2x2 tiles of mfma_f32_32x32x16_f16. 3 MFMAs per tile (hh,hl,lh).
// acc = 64 AGPR/lane -> ~164 combined regs -> 3 waves/SIMD (12 waves/CU),
// vs R2's 128x256 tile (128 AGPR -> 2 waves/SIMD, 23% occupancy).
// LDS XOR swizzle: 16B chunk at (row r, k-chunk c) stored at physical chunk
// c ^ ((r>>1)&3)  -> conflict-free ds_read_b128.
// MODE 0: write v split.  MODE 1: write fourier(v) split.
// MODE 2: write v split at col, fourier(v) split at col+Hh (layer-1 concat).
// MODE 3: dist+argmin epilogue (score = e2[col] - 2*acc, atomicMin packed key)
// ===========================================================================
template<int MODE>
__global__ __launch_bounds__(TPB, 3)
void gemm_split(const _Float16* __restrict__ Agh, const _Float16* __restrict__ Agl,
                const _Float16* __restrict__ Bgh, const _Float16* __restrict__ Bgl,
                const float* __restrict__ bias, float invscale,
                _Float16* __restrict__ Ch, _Float16* __restrict__ Cl,
                int Kd, int ldc,
                const float* __restrict__ e2, ull* __restrict__ gkey)
{
    __shared__ _Float16 sAh[128 * 32];
    __shared__ _Float16 sAl[128 * 32];
    __shared__ _Float16 sBh[128 * 32];
    __shared__ _Float16 sBl[128 * 32];
    __shared__ ull red[256];   // MODE 3 only

    const int tid = threadIdx.x, lane = tid & 63;
    const int w = tid >> 6;
    const int bn = blockIdx.x, bm = blockIdx.y;
    const int wm = w >> 1, wn = w & 1;
    const int l31 = lane & 31, lh = lane >> 5;

    // ---- staging address precompute (chunk q = s*256 + tid; r=q>>2) ----
    size_t aoff[2], boff[2];
#pragma unroll
    for (int s = 0; s < 2; ++s) {
        int q = s * 256 + tid; int r = q >> 2;
        int c = (q & 3) ^ ((r >> 1) & 3);                 // global k-chunk
        aoff[s] = (size_t)(bm * 128 + r) * Kd + c * 8;
        boff[s] = (size_t)(bn * 128 + r) * Kd + c * 8;
    }

    // ---- fragment LDS offsets ----
    int arow[2], asw[2], brow[2], bsw[2];
#pragma unroll
    for (int mt = 0; mt < 2; ++mt) {
        int r = wm * 64 + mt * 32 + l31; arow[mt] = r * 32; asw[mt] = (r >> 1) & 3;
    }
#pragma unroll
    for (int nt = 0; nt < 2; ++nt) {
        int r = wn * 64 + nt * 32 + l31; brow[nt] = r * 32; bsw[nt] = (r >> 1) & 3;
    }

    floatx16 acc[2][2];
#pragma unroll
    for (int mt = 0; mt < 2; ++mt)
#pragma unroll
        for (int nt = 0; nt < 2; ++nt)
#pragma unroll
            for (int i = 0; i < 16; ++i) acc[mt][nt][i] = 0.f;

    for (int k0 = 0; k0 < Kd; k0 += 32) {
#pragma unroll
        for (int s = 0; s < 2; ++s) {
            ASYNC_CP16(Agh + aoff[s] + k0, sAh + (s * 256 + tid) * 8);
            ASYNC_CP16(Agl + aoff[s] + k0, sAl + (s * 256 + tid) * 8);
            ASYNC_CP16(Bgh + boff[s] + k0, sBh + (s * 256 + tid) * 8);
            ASYNC_CP16(Bgl + boff[s] + k0, sBl + (s * 256 + tid) * 8);
        }
        __syncthreads();   // vmcnt(0) drain: staged data visible

#pragma unroll
        for (int kk = 0; kk < 2; ++kk) {
            const int ck = kk * 2 + lh;   // 16B k-chunk index within BK=32
            half8 ah[2], al[2], bh[2], bl[2];
#pragma unroll
            for (int mt = 0; mt < 2; ++mt) {
                int off = arow[mt] + (ck ^ asw[mt]) * 8;
                ah[mt] = *(const half8*)(sAh + off);
                al[mt] = *(const half8*)(sAl + off);
            }
#pragma unroll
            for (int nt = 0; nt < 2; ++nt) {
                int off = brow[nt] + (ck ^ bsw[nt]) * 8;
                bh[nt] = *(const half8*)(sBh + off);
                bl[nt] = *(const half8*)(sBl + off);
            }
            // hh, then hl, then lh
#pragma unroll
            for (int mt = 0; mt < 2; ++mt)
#pragma unroll
                for (int nt = 0; nt < 2; ++nt)
                    acc[mt][nt] = __builtin_amdgcn_mfma_f32_32x32x16_f16(ah[mt], bh[nt], acc[mt][nt], 0, 0, 0);
#pragma unroll
            for (int mt = 0; mt < 2; ++mt)
#pragma unroll
                for (int nt = 0; nt < 2; ++nt)
                    acc[mt][nt] = __builtin_amdgcn_mfma_f32_32x32x16_f16(ah[mt], bl[nt], acc[mt][nt], 0, 0, 0);
#pragma unroll
            for (int mt = 0; mt < 2; ++mt)
#pragma unroll
                for (int nt = 0; nt < 2; ++nt)
                    acc[mt][nt] = __builtin_amdgcn_mfma_f32_32x32x16_f16(al[mt], bh[nt], acc[mt][nt], 0, 0, 0);
        }
        __syncthreads();   // reads done before next overwrite
    }

    // ---- epilogue ----
    // C/D layout (verified m74/m101): col = lane&31, row = (reg&3)+8*(reg>>2)+4*(lane>>5)
    if (MODE != 3) {
        float bs[2];
#pragma unroll
        for (int nt = 0; nt < 2; ++nt) bs[nt] = bias[bn * 128 + wn * 64 + nt * 32 + l31];
#pragma unroll
        for (int mt = 0; mt < 2; ++mt) {
#pragma unroll
            for (int nt = 0; nt < 2; ++nt) {
                const int col = bn * 128 + wn * 64 + nt * 32 + l31;
#pragma unroll
                for (int r = 0; r < 16; ++r) {
                    const int mrow = (r & 3) + 8 * (r >> 2) + 4 * lh;
                    const size_t row = (size_t)(bm * 128 + wm * 64 + mt * 32 + mrow);
                    const float v = acc[mt][nt][r] * invscale + bs[nt];
                    const size_t o = row * ldc + col;
                    if (MODE == 0) {
                        _Float16 h = (_Float16)v;
                        Ch[o] = h; Cl[o] = (_Float16)(v - (float)h);
                    } else if (MODE == 1) {
                        float f = fourier1(col, v);
                        _Float16 h = (_Float16)f;
                        Ch[o] = h; Cl[o] = (_Float16)(f - (float)h);
                    } else {
                        _Float16 h = (_Float16)v;
                        Ch[o] = h; Cl[o] = (_Float16)(v - (float)h);
                        float f = fourier1(col, v);
                        _Float16 hf = (_Float16)f;
                        Ch[o + Hh] = hf; Cl[o + Hh] = (_Float16)(f - (float)hf);
                    }
                }
            }
        }
    } else {
        float es[2];
#pragma unroll
        for (int nt = 0; nt < 2; ++nt) es[nt] = e2[bn * 128 + wn * 64 + nt * 32 + l31];
#pragma unroll
        for (int mt = 0; mt < 2; ++mt) {
#pragma unroll
            for (int r = 0; r < 16; ++r) {
                ull best = ~0ull;
#pragma unroll
                for (int nt = 0; nt < 2; ++nt) {
                    const int col = bn * 128 + wn * 64 + nt * 32 + l31;
                    float sc = es[nt] - 2.0f * acc[mt][nt][r];
                    unsigned u = __float_as_uint(sc);
                    u = (u & 0x80000000u) ? ~u : (u | 0x80000000u);  // monotone map
                    ull key = ((ull)u << 32) | (unsigned)col;
                    best = best < key ? best : key;
                }
                // min over 32 cols (lanes 0-31 and 32-63 reduce independently;
                // the two halves hold different rows)
#pragma unroll
                for (int m = 16; m >= 1; m >>= 1) {
                    ull o = __shfl_xor(best, m, 64);
                    best = best < o ? best : o;
                }
                if (l31 == 0) {
                    int rl = wm * 64 + mt * 32 + (r & 3) + 8 * (r >> 2) + 4 * lh;
                    red[rl * 2 + wn] = best;
                }
            }
        }
        __syncthreads();
        if (tid < 128) {
            ull a = red[tid * 2], b = red[tid * 2 + 1];
            atomicMin(&gkey[(size_t)bm * 128 + tid], a < b ? a : b);
        }
    }
}

// fp32 -> (hi, lo) fp16 planes, optionally pre-scaled (scale = power of 2)
__global__ void split_f16(const float* __restrict__ src, _Float16* __restrict__ hi,
                          _Float16* __restrict__ lo, int n8, float scale)
{
    int i = blockIdx.x * blockDim.x + threadIdx.x;
    if (i >= n8) return;
    const float4* s4 = (const float4*)src;
    float4 v0 = s4[i * 2], v1 = s4[i * 2 + 1];
    float v[8] = {v0.x, v0.y, v0.z, v0.w, v1.x, v1.y, v1.z, v1.w};
    half8 h, l;
#pragma unroll
    for (int j = 0; j < 8; ++j) {
        float x = v[j] * scale;
        _Float16 hh = (_Float16)x;
        h[j] = hh;
        l[j] = (_Float16)(x - (float)hh);
    }
    *(half8*)(hi + (size_t)i * 8) = h;
    *(half8*)(lo + (size_t)i * 8) = l;
}

// ===========================================================================
// Shared small kernels
// ===========================================================================
__global__ void init_gkey(ull* gkey) {
    int i = blockIdx.x * blockDim.x + threadIdx.x;
    if (i < NB) gkey[i] = ~0ull;
}

__global__ void e2_kernel(const float* __restrict__ emb, float* __restrict__ e2) {
    int k = blockIdx.x, t = threadIdx.x;
    float s = 0.f;
    for (int d = t; d < Dd; d += 256) {
        float v = emb[(size_t)k * Dd + d];
        s += v * v;
    }
    __shared__ float r[256];
    r[t] = s; __syncthreads();
    for (int off = 128; off > 0; off >>= 1) {
        if (t < off) r[t] += r[t + off];
        __syncthreads();
    }
    if (t == 0) e2[k] = r[0];
}

__device__ __forceinline__ long long mueller(long long x) {
    x = (long long)((unsigned long long)(x ^ (x >> 16)) * 73244475ull);
    x = (long long)((unsigned long long)(x ^ (x >> 16)) * 73244475ull);
    return x ^ (x >> 16);
}

__global__ void out_kernel(const float* __restrict__ emb,
                           const ull* __restrict__ gkey,
                           float* __restrict__ out) {
    const int n = blockIdx.x;
    const int t = threadIdx.x;
    long long idx = (long long)(unsigned)(gkey[n] & 0xFFFFFFFFull);
    int s1 = (int)(mueller(idx + 1LL * Kc) & (long long)(Kc - 1));
    int s2 = (int)(mueller(idx + 2LL * Kc) & (long long)(Kc - 1));
    int s3 = (int)(mueller(idx + 3LL * Kc) & (long long)(Kc - 1));
    const float* e1p = emb + (size_t)s1 * Dd;
    const float* e2p = emb + (size_t)s2 * Dd;
    const float* e3p = emb + (size_t)s3 * Dd;
    float* op = out + (size_t)n * Dd;
    for (int d = t; d < Dd; d += 256)
        op[d] = e1p[d] / 3.0f + e2p[d] / 3.0f + e3p[d] / 3.0f;
}

// ===========================================================================
// Fallback fp32 path (round-1, proven) — used only if ws_size < 512 MiB
// ===========================================================================
__device__ __forceinline__ float fourier1p(int col, float v) {
    return (col & 1) ? cosf(v) : sinf(v);
}

template<int MODE>
__global__ __launch_bounds__(TPB)
void gemm_tn(const float* __restrict__ A, const float* __restrict__ B,
             const float* __restrict__ bias, float* __restrict__ C,
             int Kd, int ldc)
{
    __shared__ float As[16][132];
    __shared__ float Bs[16][132];
    const int t  = threadIdx.x;
    const int bn = blockIdx.x, bm = blockIdx.y;
    const int rowL = t >> 2;
    const int kq   = t & 3;
    const int rm   = (t >> 4) << 3;
    const int rn   = (t & 15) << 3;

    const float* Ab = A + (size_t)(bm * 128 + rowL) * Kd + kq * 4;
    const float* Bb = B + (size_t)(bn * 128 + rowL) * Kd + kq * 4;
    const size_t strideHalf = (size_t)64 * Kd;

    float acc[8][8];
#pragma unroll
    for (int i = 0; i < 8; ++i)
#pragma unroll
        for (int j = 0; j < 8; ++j) acc[i][j] = 0.f;

    for (int k0 = 0; k0 < Kd; k0 += 16) {
        float4 a0 = *(const float4*)(Ab + k0);
        float4 a1 = *(const float4*)(Ab + strideHalf + k0);
        float4 b0 = *(const float4*)(Bb + k0);
        float4 b1 = *(const float4*)(Bb + strideHalf + k0);
        __syncthreads();
        As[kq*4+0][rowL]    = a0.x; As[kq*4+1][rowL]    = a0.y;
        As[kq*4+2][rowL]    = a0.z; As[kq*4+3][rowL]    = a0.w;
        As[kq*4+0][rowL+64] = a1.x; As[kq*4+1][rowL+64] = a1.y;
        As[kq*4+2][rowL+64] = a1.z; As[kq*4+3][rowL+64] = a1.w;
        Bs[kq*4+0][rowL]    = b0.x; Bs[kq*4+1][rowL]    = b0.y;
        Bs[kq*4+2][rowL]    = b0.z; Bs[kq*4+3][rowL]    = b0.w;
        Bs[kq*4+0][rowL+64] = b1.x; Bs[kq*4+1][rowL+64] = b1.y;
        Bs[kq*4+2][rowL+64] = b1.z; Bs[kq*4+3][rowL+64] = b1.w;
        __syncthreads();
#pragma unroll
        for (int kk = 0; kk < 16; ++kk) {
            float4 av0 = *(const float4*)&As[kk][rm];
            float4 av1 = *(const float4*)&As[kk][rm + 4];
            float4 bv0 = *(const float4*)&Bs[kk][rn];
            float4 bv1 = *(const float4*)&Bs[kk][rn + 4];
            float a[8] = {av0.x, av0.y, av0.z, av0.w, av1.x, av1.y, av1.z, av1.w};
            float b[8] = {bv0.x, bv0.y, bv0.z, bv0.w, bv1.x, bv1.y, bv1.z, bv1.w};
#pragma unroll
            for (int i = 0; i < 8; ++i)
#pragma unroll
                for (int j = 0; j < 8; ++j)
                    acc[i][j] = fmaf(a[i], b[j], acc[i][j]);
        }
    }

    const int gm = bm * 128 + rm;
    const int gn = bn * 128 + rn;
#pragma unroll
    for (int i = 0; i < 8; ++i) {
#pragma unroll
        for (int j = 0; j < 8; ++j) {
            float v = acc[i][j] + bias[gn + j];
            size_t o = (size_t)(gm + i) * ldc + (gn + j);
            if (MODE == 0) {
                C[o] = v;
            } else if (MODE == 1) {
                C[o] = fourier1p(gn + j, v);
            } else {
                C[o]      = v;
                C[o + Hh] = fourier1p(gn + j, v);
            }
        }
    }
}

__global__ __launch_bounds__(TPB)
void dist_argmin(const float* __restrict__ Z, const float* __restrict__ E,
                 const float* __restrict__ e2, ull* __restrict__ gkey)
{
    __shared__ float As[16][132];
    __shared__ float Bs[16][132];
    __shared__ ull   red[128][16];
    const int t  = threadIdx.x;
    const int bn = blockIdx.x, bm = blockIdx.y;
    const int rowL = t >> 2;
    const int kq   = t & 3;
    const int rm   = (t >> 4) << 3;
    const int rn   = (t & 15) << 3;
    const int Kd = Dd;

    const float* Ab = Z + (size_t)(bm * 128 + rowL) * Kd + kq * 4;
    const float* Bb = E + (size_t)(bn * 128 + rowL) * Kd + kq * 4;
    const size_t strideHalf = (size_t)64 * Kd;

    float acc[8][8];
#pragma unroll
    for (int i = 0; i < 8; ++i)
#pragma unroll
        for (int j = 0; j < 8; ++j) acc[i][j] = 0.f;

    for (int k0 = 0; k0 < Kd; k0 += 16) {
        float4 a0 = *(const float4*)(Ab + k0);
        float4 a1 = *(const float4*)(Ab + strideHalf + k0);
        float4 b0 = *(const float4*)(Bb + k0);
        float4 b1 = *(const float4*)(Bb + strideHalf + k0);
        __syncthreads();
        As[kq*4+0][rowL]    = a0.x; As[kq*4+1][rowL]    = a0.y;
        As[kq*4+2][rowL]    = a0.z; As[kq*4+3][rowL]    = a0.w;
        As[kq*4+0][rowL+64] = a1.x; As[kq*4+1][rowL+64] = a1.y;
        As[kq*4+2][rowL+64] = a1.z; As[kq*4+3][rowL+64] = a1.w;
        Bs[kq*4+0][rowL]    = b0.x; Bs[kq*4+1][rowL]    = b0.y;
        Bs[kq*4+2][rowL]    = b0.z; Bs[kq*4+3][rowL]    = b0.w;
        Bs[kq*4+0][rowL+64] = b1.x; Bs[kq*4+1][rowL+64] = b1.y;
        Bs[kq*4+2][rowL+64] = b1.z; Bs[kq*4+3][rowL+64] = b1.w;
        __syncthreads();
#pragma unroll
        for (int kk = 0; kk < 16; ++kk) {
            float4 av0 = *(const float4*)&As[kk][rm];
            float4 av1 = *(const float4*)&As[kk][rm + 4];
            float4 bv0 = *(const float4*)&Bs[kk][rn];
            float4 bv1 = *(const float4*)&Bs[kk][rn + 4];
            float a[8] = {av0.x, av0.y, av0.z, av0.w, av1.x, av1.y, av1.z, av1.w};
            float b[8] = {bv0.x, bv0.y, bv0.z, bv0.w, bv1.x, bv1.y, bv1.z, bv1.w};
#pragma unroll
            for (int i = 0; i < 8; ++i)
#pragma unroll
                for (int j = 0; j < 8; ++j)
                    acc[i][j] = fmaf(a[i], b[j], acc[i][j]);
        }
    }

    const int gn = bn * 128 + rn;
#pragma unroll
    for (int i = 0; i < 8; ++i) {
        ull best = ~0ull;
#pragma unroll
        for (int j = 0; j < 8; ++j) {
            int gk = gn + j;
            float sc = e2[gk] - 2.0f * acc[i][j];
            unsigned u = __float_as_uint(sc);
            u = (u & 0x80000000u) ? ~u : (u | 0x80000000u);
            ull key = ((ull)u << 32) | (unsigned)gk;
            best = best < key ? best : key;
        }
        red[rm + i][t & 15] = best;
    }
    __syncthreads();
    if (t < 128) {
        ull m = red[t][0];
#pragma unroll
        for (int q = 1; q < 16; ++q) m = m < red[t][q] ? m : red[t][q];
        atomicMin(&gkey[(size_t)bm * 128 + t], m);
    }
}

// ===========================================================================
extern "C" void kernel_launch(void* const* d_in, const int* in_sizes, int n_in,
                              void* d_out, int out_size, void* d_ws, size_t ws_size,
                              hipStream_t stream) {
    const float* x   = (const float*)d_in[0];
    const float* w1  = (const float*)d_in[1];
    const float* b1  = (const float*)d_in[2];
    const float* w2  = (const float*)d_in[3];
    const float* b2  = (const float*)d_in[4];
    const float* w3  = (const float*)d_in[5];
    const float* b3  = (const float*)d_in[6];
    const float* w4  = (const float*)d_in[7];
    const float* b4  = (const float*)d_in[8];
    const float* emb = (const float*)d_in[9];
    float* out = (float*)d_out;

    const size_t MB = 1024 * 1024;

    if (ws_size >= 512 * MB) {
        // ---------------- fast split-fp16 MFMA path ----------------
        // Arena (512 MiB), overlaid by liveness:
        //  R1 @0     (256): hcat planes (GEMM1->GEMM2); then w3/w4/emb planes + e2 + gkey
        //  R2 @256MB (128): w2 planes (->GEMM2); then h3 planes
        //  R3 @384MB (128): x + w1 planes (->GEMM1); then h2 planes
        char* W = (char*)d_ws;
        _Float16* hcat_h = (_Float16*)(W);
        _Float16* hcat_l = (_Float16*)(W + 128 * MB);
        _Float16* w3h = (_Float16*)(W);
        _Float16* w3l = (_Float16*)(W + 32 * MB);
        _Float16* w4h = (_Float16*)(W + 64 * MB);
        _Float16* w4l = (_Float16*)(W + 72 * MB);
        _Float16* eh  = (_Float16*)(W + 80 * MB);
        _Float16* el  = (_Float16*)(W + 88 * MB);
        float*    e2b = (float*)   (W + 96 * MB);
        ull*      gkey = (ull*)    (W + 96 * MB + 16 * 1024);
        _Float16* w2h = (_Float16*)(W + 256 * MB);
        _Float16* w2l = (_Float16*)(W + 320 * MB);
        _Float16* h3h = (_Float16*)(W + 256 * MB);
        _Float16* h3l = (_Float16*)(W + 320 * MB);
        _Float16* xh  = (_Float16*)(W + 384 * MB);
        _Float16* xl  = (_Float16*)(W + 400 * MB);
        _Float16* w1h = (_Float16*)(W + 416 * MB);
        _Float16* w1l = (_Float16*)(W + 424 * MB);
        _Float16* h2h = (_Float16*)(W + 384 * MB);
        _Float16* h2l = (_Float16*)(W + 448 * MB);
        _Float16* zh  = (_Float16*)d_out;            // z split lives in d_out
        _Float16* zl  = zh + (size_t)NB * Dd;

        const float WS = 64.0f, IWS = 1.0f / 64.0f;  // weight pre-scale (pow2):
        // keeps lo-plane of sigma=0.02 weights out of fp16 subnormal/FTZ range

        split_f16<<<dim3(1048576 / 256), 256, 0, stream>>>(x,  xh,  xl,  1048576, 1.0f);
        split_f16<<<dim3(524288  / 256), 256, 0, stream>>>(w1, w1h, w1l, 524288,  WS);
        split_f16<<<dim3(4194304 / 256), 256, 0, stream>>>(w2, w2h, w2l, 4194304, WS);

        // L1: hcat = [h, fourier(h)], h = x@w1^T + b1
        gemm_split<2><<<dim3(Hh / 128, NB / 128), TPB, 0, stream>>>(
            xh, xl, w1h, w1l, b1, IWS, hcat_h, hcat_l, Dd, 2 * Hh, nullptr, nullptr);
        // L2: h2 = fourier(hcat@w2^T + b2)
        gemm_split<1><<<dim3(Hh / 128, NB / 128), TPB, 0, stream>>>(
            hcat_h, hcat_l, w2h, w2l, b2, IWS, h2h, h2l, 2 * Hh, Hh, nullptr, nullptr);

        // hcat dead -> convert remaining operands into R1
        split_f16<<<dim3(2097152 / 256), 256, 0, stream>>>(w3,  w3h, w3l, 2097152, WS);
        split_f16<<<dim3(524288  / 256), 256, 0, stream>>>(w4,  w4h, w4l, 524288,  WS);
        split_f16<<<dim3(524288  / 256), 256, 0, stream>>>(emb, eh,  el,  524288,  1.0f);
        e2_kernel<<<dim3(Kc), dim3(256), 0, stream>>>(emb, e2b);
        init_gkey<<<dim3(NB / 256), dim3(256), 0, stream>>>(gkey);

        // L3: h3 = fourier(h2@w3^T + b3)
        gemm_split<1><<<dim3(Hh / 128, NB / 128), TPB, 0, stream>>>(
            h2h, h2l, w3h, w3l, b3, IWS, h3h, h3l, Hh, Hh, nullptr, nullptr);
        // L4: z = h3@w4^T + b4
        gemm_split<0><<<dim3(Dd / 128, NB / 128), TPB, 0, stream>>>(
            h3h, h3l, w4h, w4l, b4, IWS, zh, zl, Hh, Dd, nullptr, nullptr);
        // argmin over codes
        gemm_split<3><<<dim3(Kc / 128, NB / 128), TPB, 0, stream>>>(
            zh, zl, eh, el, nullptr, 1.0f, nullptr, nullptr, Dd, 0, e2b, gkey);

        out_kernel<<<dim3(NB), dim3(256), 0, stream>>>(emb, gkey, out);
    } else {
        // ---------------- fallback fp32 path (round-1) ----------------
        float* hcat  = (float*)d_ws;
        float* h2    = hcat + (size_t)NB * 2 * Hh;
        float* e2buf = h2 + (size_t)NB * Hh;
        ull*   gkey  = (ull*)(e2buf + Kc);
        float* h3    = hcat;

        init_gkey<<<dim3((NB + 255) / 256), dim3(256), 0, stream>>>(gkey);
        e2_kernel<<<dim3(Kc), dim3(256), 0, stream>>>(emb, e2buf);
        gemm_tn<2><<<dim3(Hh / 128, NB / 128), TPB, 0, stream>>>(x, w1, b1, hcat, Dd, 2 * Hh);
        gemm_tn<1><<<dim3(Hh / 128, NB / 128), TPB, 0, stream>>>(hcat, w2, b2, h2, 2 * Hh, Hh);
        gemm_tn<1><<<dim3(Hh / 128, NB / 128), TPB, 0, stream>>>(h2, w3, b3, h3, Hh, Hh);
        gemm_tn<0><<<dim3(Dd / 128, NB / 128), TPB, 0, stream>>>(h3, w4, b4, out, Hh, Dd);
        dist_argmin<<<dim3(Kc / 128, NB / 128), TPB, 0, stream>>>(out, emb, e2buf, gkey);
        out_kernel<<<dim3(NB), dim3(256), 0, stream>>>(emb, gkey, out);
    }
}

// Round 4
// 3365.924 us; speedup vs baseline: 1.3261x; 1.3261x over previous
//
#include <hip/hip_runtime.h>
#include <cstdint>

// Problem constants
constexpr int NB = 8192;   // batch rows
constexpr int Dd = 1024;   // feature dim
constexpr int Hh = 4096;   // hidden
constexpr int Kc = 4096;   // codebook size

using ull = unsigned long long;
typedef _Float16 half8 __attribute__((ext_vector_type(8)));
typedef float floatx16 __attribute__((ext_vector_type(16)));

#define TPB 256

__device__ __forceinline__ float fourier1(int col, float v) {
    // even feature index -> sin, odd -> cos
    return (col & 1) ? __cosf(v) : __sinf(v);
}

// async global->LDS, 16B per lane (global_load_lds_dwordx4)
#define ASYNC_CP16(gp, sp)                                                          \
    __builtin_amdgcn_global_load_lds(                                               \
        (const __attribute__((address_space(1))) unsigned int*)(gp),                \
        (__attribute__((address_space(3))) unsigned int*)(sp), 16, 0, 0)

// ===========================================================================
// A-operand fragment-tiled layout (for activations):
//   element (m, k) of a plane lives at
//     ((m>>5)*(Kd>>4) + (k>>4))*512 + ((k>>3)&1)*256 + (m&31)*8 + (k&7)
//   so one mfma_32x32x16 A-fragment (rows m0..m0+31, k-chunk of 16) is a
//   contiguous 1 KB block; lane l reads 16 B at base + l*16 — one coalesced
//   global_load_dwordx4, no LDS involvement.
// Rationale (R3 post-mortem): all-LDS operands cap MfmaUtil at ~50%
// (LDS ~128 B/cyc vs 256 B/cyc operand demand at 64x128 wave tile).
// Splitting A to the L1/VMEM pipe balances LDS(B) ~1024cyc vs L1(A) ~1024cyc
// vs MFMA 768cyc per staging interval.
// ===========================================================================

// ===========================================================================
// Split-fp16 MFMA GEMM:  C = (A @ B^T) * invscale + bias, fused epilogue.
// A: fragment-tiled hi/lo fp16 planes (see above). B: [N][Kd] row-major
// hi/lo planes, LDS-staged with XOR swizzle (conflict-free ds_read_b128).
// Block tile 128(M) x 256(N), BK=32, 256 threads = 4 waves (2x2), wave tile
// 64x128 = 2x4 tiles of mfma_f32_32x32x16_f16. 3 MFMAs per tile (hh,hl,lh).
// MODE 0/1/2 epilogues write the output as fragment-tiled planes (it is the
// next GEMM's A). MODE 2 additionally writes fourier(v) at col+Hh.
// MODE 3: dist+argmin epilogue (score = e2[col] - 2*acc, atomicMin packed key)
// ===========================================================================
template<int MODE>
__global__ __launch_bounds__(TPB, 2)
void gemm_split(const _Float16* __restrict__ Agh, const _Float16* __restrict__ Agl,
                const _Float16* __restrict__ Bgh, const _Float16* __restrict__ Bgl,
                const float* __restrict__ bias, float invscale,
                _Float16* __restrict__ Ch, _Float16* __restrict__ Cl,
                int Kd, int ldc,
                const float* __restrict__ e2, ull* __restrict__ gkey)
{
    __shared__ _Float16 sBh[256 * 32];
    __shared__ _Float16 sBl[256 * 32];
    __shared__ ull red[256];   // MODE 3 only

    const int tid = threadIdx.x, lane = tid & 63;
    const int w = tid >> 6;
    const int bn = blockIdx.x, bm = blockIdx.y;
    const int wm = w >> 1, wn = w & 1;
    const int l31 = lane & 31, lh = lane >> 5;
    const int kpf = Kd >> 4;   // k-chunks (16-elem) per row

    // ---- B staging address precompute (4 chunks/plane; q = s*256+tid) ----
    size_t boff[4];
#pragma unroll
    for (int s = 0; s < 4; ++s) {
        int q = s * 256 + tid; int r = q >> 2;
        int c = (q & 3) ^ ((r >> 1) & 3);                 // global k-chunk
        boff[s] = (size_t)(bn * 256 + r) * Kd + c * 8;
    }

    // ---- B fragment LDS offsets ----
    int brow[4], bsw[4];
#pragma unroll
    for (int nt = 0; nt < 4; ++nt) {
        int r = wn * 128 + nt * 32 + l31; brow[nt] = r * 32; bsw[nt] = (r >> 1) & 3;
    }

    // ---- A fragment global bases (fragment-tiled layout) ----
    size_t abase[2];
#pragma unroll
    for (int mt = 0; mt < 2; ++mt)
        abase[mt] = (size_t)(bm * 4 + wm * 2 + mt) * kpf * 512 + (size_t)lane * 8;

    floatx16 acc[2][4];
#pragma unroll
    for (int mt = 0; mt < 2; ++mt)
#pragma unroll
        for (int nt = 0; nt < 4; ++nt)
#pragma unroll
            for (int i = 0; i < 16; ++i) acc[mt][nt][i] = 0.f;

    for (int k0 = 0, ki = 0; k0 < Kd; k0 += 32, ki += 2) {
        // stage B tile into LDS (async), prefetch A fragments into VGPRs
#pragma unroll
        for (int s = 0; s < 4; ++s) {
            ASYNC_CP16(Bgh + boff[s] + k0, sBh + (s * 256 + tid) * 8);
            ASYNC_CP16(Bgl + boff[s] + k0, sBl + (s * 256 + tid) * 8);
        }
        half8 ahr[2][2], alr[2][2];
#pragma unroll
        for (int kk = 0; kk < 2; ++kk)
#pragma unroll
            for (int mt = 0; mt < 2; ++mt) {
                size_t o = abase[mt] + (size_t)(ki + kk) * 512;
                ahr[kk][mt] = *(const half8*)(Agh + o);
                alr[kk][mt] = *(const half8*)(Agl + o);
            }
        __syncthreads();   // vmcnt(0) drain: staged B visible (A already in regs)

#pragma unroll
        for (int kk = 0; kk < 2; ++kk) {
            const int ck = kk * 2 + lh;   // 16B k-chunk index within BK=32
            half8 bh[4], bl[4];
#pragma unroll
            for (int nt = 0; nt < 4; ++nt) {
                int off = brow[nt] + (ck ^ bsw[nt]) * 8;
                bh[nt] = *(const half8*)(sBh + off);
                bl[nt] = *(const half8*)(sBl + off);
            }
            // hh, then hl, then lh
#pragma unroll
            for (int mt = 0; mt < 2; ++mt)
#pragma unroll
                for (int nt = 0; nt < 4; ++nt)
                    acc[mt][nt] = __builtin_amdgcn_mfma_f32_32x32x16_f16(ahr[kk][mt], bh[nt], acc[mt][nt], 0, 0, 0);
#pragma unroll
            for (int mt = 0; mt < 2; ++mt)
#pragma unroll
                for (int nt = 0; nt < 4; ++nt)
                    acc[mt][nt] = __builtin_amdgcn_mfma_f32_32x32x16_f16(ahr[kk][mt], bl[nt], acc[mt][nt], 0, 0, 0);
#pragma unroll
            for (int mt = 0; mt < 2; ++mt)
#pragma unroll
                for (int nt = 0; nt < 4; ++nt)
                    acc[mt][nt] = __builtin_amdgcn_mfma_f32_32x32x16_f16(alr[kk][mt], bh[nt], acc[mt][nt], 0, 0, 0);
        }
        __syncthreads();   // LDS reads done before next overwrite
    }

    // ---- epilogue ----
    // C/D layout (verified m74/m101): col = lane&31, row = (reg&3)+8*(reg>>2)+4*(lane>>5)
    if (MODE != 3) {
        const int kpo = ldc >> 4;   // output plane k-chunks per row
        float bs[4];
#pragma unroll
        for (int nt = 0; nt < 4; ++nt) bs[nt] = bias[bn * 256 + wn * 128 + nt * 32 + l31];
#pragma unroll
        for (int mt = 0; mt < 2; ++mt) {
            const size_t rowblk = (size_t)(bm * 4 + wm * 2 + mt) * kpo;
#pragma unroll
            for (int nt = 0; nt < 4; ++nt) {
                const int col = bn * 256 + wn * 128 + nt * 32 + l31;
                const size_t fb  = (rowblk + (col >> 4)) * 512 + ((col >> 3) & 1) * 256 + (col & 7);
                const size_t fb2 = fb + (size_t)256 * 512;   // col + Hh (Hh=4096 -> +256 chunks)
#pragma unroll
                for (int r = 0; r < 16; ++r) {
                    const int mrow = (r & 3) + 8 * (r >> 2) + 4 * lh;
                    const float v = acc[mt][nt][r] * invscale + bs[nt];
                    const size_t o = fb + mrow * 8;
                    if (MODE == 0) {
                        _Float16 h = (_Float16)v;
                        Ch[o] = h; Cl[o] = (_Float16)(v - (float)h);
                    } else if (MODE == 1) {
                        float f = fourier1(col, v);
                        _Float16 h = (_Float16)f;
                        Ch[o] = h; Cl[o] = (_Float16)(f - (float)h);
                    } else {
                        _Float16 h = (_Float16)v;
                        Ch[o] = h; Cl[o] = (_Float16)(v - (float)h);
                        float f = fourier1(col, v);
                        _Float16 hf = (_Float16)f;
                        Ch[fb2 + mrow * 8] = hf; Cl[fb2 + mrow * 8] = (_Float16)(f - (float)hf);
                    }
                }
            }
        }
    } else {
        float es[4];
#pragma unroll
        for (int nt = 0; nt < 4; ++nt) es[nt] = e2[bn * 256 + wn * 128 + nt * 32 + l31];
#pragma unroll
        for (int mt = 0; mt < 2; ++mt) {
#pragma unroll
            for (int r = 0; r < 16; ++r) {
                ull best = ~0ull;
#pragma unroll
                for (int nt = 0; nt < 4; ++nt) {
                    const int col = bn * 256 + wn * 128 + nt * 32 + l31;
                    float sc = es[nt] - 2.0f * acc[mt][nt][r];
                    unsigned u = __float_as_uint(sc);
                    u = (u & 0x80000000u) ? ~u : (u | 0x80000000u);  // monotone map
                    ull key = ((ull)u << 32) | (unsigned)col;
                    best = best < key ? best : key;
                }
                // min over 32 cols (lanes 0-31 / 32-63 hold different rows)
#pragma unroll
                for (int m = 16; m >= 1; m >>= 1) {
                    ull o = __shfl_xor(best, m, 64);
                    best = best < o ? best : o;
                }
                if (l31 == 0) {
                    int rl = wm * 64 + mt * 32 + (r & 3) + 8 * (r >> 2) + 4 * lh;
                    red[rl * 2 + wn] = best;
                }
            }
        }
        __syncthreads();
        if (tid < 128) {
            ull a = red[tid * 2], b = red[tid * 2 + 1];
            atomicMin(&gkey[(size_t)bm * 128 + tid], a < b ? a : b);
        }
    }
}

// fp32 -> (hi, lo) fp16 planes, row-major (B-side operands: weights, emb)
__global__ void split_f16(const float* __restrict__ src, _Float16* __restrict__ hi,
                          _Float16* __restrict__ lo, int n8, float scale)
{
    int i = blockIdx.x * blockDim.x + threadIdx.x;
    if (i >= n8) return;
    const float4* s4 = (const float4*)src;
    float4 v0 = s4[i * 2], v1 = s4[i * 2 + 1];
    float v[8] = {v0.x, v0.y, v0.z, v0.w, v1.x, v1.y, v1.z, v1.w};
    half8 h, l;
#pragma unroll
    for (int j = 0; j < 8; ++j) {
        float x = v[j] * scale;
        _Float16 hh = (_Float16)x;
        h[j] = hh;
        l[j] = (_Float16)(x - (float)hh);
    }
    *(half8*)(hi + (size_t)i * 8) = h;
    *(half8*)(lo + (size_t)i * 8) = l;
}

// fp32 row-major -> (hi, lo) fp16 planes in A-fragment-tiled layout (for x)
__global__ void split_f16_frag(const float* __restrict__ src, _Float16* __restrict__ hi,
                               _Float16* __restrict__ lo, int n8, int Kd)
{
    int i = blockIdx.x * blockDim.x + threadIdx.x;
    if (i >= n8) return;
    // dest: frag-flat slot i (8 elems, 16B) — coalesced stores
    int e = i * 8;
    int f = e >> 9;              // fragment id
    int ww = e & 511;
    int khalf = ww >> 8, row32 = (ww >> 3) & 31;
    int kpf = Kd >> 4;
    int rowblk = f / kpf, kch = f - rowblk * kpf;
    int m = rowblk * 32 + row32, k = kch * 16 + khalf * 8;
    const float* s = src + (size_t)m * Kd + k;
    half8 h, l;
#pragma unroll
    for (int j = 0; j < 8; ++j) {
        float x = s[j];
        _Float16 hh = (_Float16)x;
        h[j] = hh;
        l[j] = (_Float16)(x - (float)hh);
    }
    *(half8*)(hi + (size_t)i * 8) = h;
    *(half8*)(lo + (size_t)i * 8) = l;
}

// ===========================================================================
// Shared small kernels
// ===========================================================================
__global__ void init_gkey(ull* gkey) {
    int i = blockIdx.x * blockDim.x + threadIdx.x;
    if (i < NB) gkey[i] = ~0ull;
}

__global__ void e2_kernel(const float* __restrict__ emb, float* __restrict__ e2) {
    int k = blockIdx.x, t = threadIdx.x;
    float s = 0.f;
    for (int d = t; d < Dd; d += 256) {
        float v = emb[(size_t)k * Dd + d];
        s += v * v;
    }
    __shared__ float r[256];
    r[t] = s; __syncthreads();
    for (int off = 128; off > 0; off >>= 1) {
        if (t < off) r[t] += r[t + off];
        __syncthreads();
    }
    if (t == 0) e2[k] = r[0];
}

__device__ __forceinline__ long long mueller(long long x) {
    x = (long long)((unsigned long long)(x ^ (x >> 16)) * 73244475ull);
    x = (long long)((unsigned long long)(x ^ (x >> 16)) * 73244475ull);
    return x ^ (x >> 16);
}

__global__ void out_kernel(const float* __restrict__ emb,
                           const ull* __restrict__ gkey,
                           float* __restrict__ out) {
    const int n = blockIdx.x;
    const int t = threadIdx.x;
    long long idx = (long long)(unsigned)(gkey[n] & 0xFFFFFFFFull);
    int s1 = (int)(mueller(idx + 1LL * Kc) & (long long)(Kc - 1));
    int s2 = (int)(mueller(idx + 2LL * Kc) & (long long)(Kc - 1));
    int s3 = (int)(mueller(idx + 3LL * Kc) & (long long)(Kc - 1));
    const float* e1p = emb + (size_t)s1 * Dd;
    const float* e2p = emb + (size_t)s2 * Dd;
    const float* e3p = emb + (size_t)s3 * Dd;
    float* op = out + (size_t)n * Dd;
    for (int d = t; d < Dd; d += 256)
        op[d] = e1p[d] / 3.0f + e2p[d] / 3.0f + e3p[d] / 3.0f;
}

// ===========================================================================
// Fallback fp32 path (round-1, proven) — used only if ws_size < 512 MiB
// ===========================================================================
__device__ __forceinline__ float fourier1p(int col, float v) {
    return (col & 1) ? cosf(v) : sinf(v);
}

template<int MODE>
__global__ __launch_bounds__(TPB)
void gemm_tn(const float* __restrict__ A, const float* __restrict__ B,
             const float* __restrict__ bias, float* __restrict__ C,
             int Kd, int ldc)
{
    __shared__ float As[16][132];
    __shared__ float Bs[16][132];
    const int t  = threadIdx.x;
    const int bn = blockIdx.x, bm = blockIdx.y;
    const int rowL = t >> 2;
    const int kq   = t & 3;
    const int rm   = (t >> 4) << 3;
    const int rn   = (t & 15) << 3;

    const float* Ab = A + (size_t)(bm * 128 + rowL) * Kd + kq * 4;
    const float* Bb = B + (size_t)(bn * 128 + rowL) * Kd + kq * 4;
    const size_t strideHalf = (size_t)64 * Kd;

    float acc[8][8];
#pragma unroll
    for (int i = 0; i < 8; ++i)
#pragma unroll
        for (int j = 0; j < 8; ++j) acc[i][j] = 0.f;

    for (int k0 = 0; k0 < Kd; k0 += 16) {
        float4 a0 = *(const float4*)(Ab + k0);
        float4 a1 = *(const float4*)(Ab + strideHalf + k0);
        float4 b0 = *(const float4*)(Bb + k0);
        float4 b1 = *(const float4*)(Bb + strideHalf + k0);
        __syncthreads();
        As[kq*4+0][rowL]    = a0.x; As[kq*4+1][rowL]    = a0.y;
        As[kq*4+2][rowL]    = a0.z; As[kq*4+3][rowL]    = a0.w;
        As[kq*4+0][rowL+64] = a1.x; As[kq*4+1][rowL+64] = a1.y;
        As[kq*4+2][rowL+64] = a1.z; As[kq*4+3][rowL+64] = a1.w;
        Bs[kq*4+0][rowL]    = b0.x; Bs[kq*4+1][rowL]    = b0.y;
        Bs[kq*4+2][rowL]    = b0.z; Bs[kq*4+3][rowL]    = b0.w;
        Bs[kq*4+0][rowL+64] = b1.x; Bs[kq*4+1][rowL+64] = b1.y;
        Bs[kq*4+2][rowL+64] = b1.z; Bs[kq*4+3][rowL+64] = b1.w;
        __syncthreads();
#pragma unroll
        for (int kk = 0; kk < 16; ++kk) {
            float4 av0 = *(const float4*)&As[kk][rm];
            float4 av1 = *(const float4*)&As[kk][rm + 4];
            float4 bv0 = *(const float4*)&Bs[kk][rn];
            float4 bv1 = *(const float4*)&Bs[kk][rn + 4];
            float a[8] = {av0.x, av0.y, av0.z, av0.w, av1.x, av1.y, av1.z, av1.w};
            float b[8] = {bv0.x, bv0.y, bv0.z, bv0.w, bv1.x, bv1.y, bv1.z, bv1.w};
#pragma unroll
            for (int i = 0; i < 8; ++i)
#pragma unroll
                for (int j = 0; j < 8; ++j)
                    acc[i][j] = fmaf(a[i], b[j], acc[i][j]);
        }
    }

    const int gm = bm * 128 + rm;
    const int gn = bn * 128 + rn;
#pragma unroll
    for (int i = 0; i < 8; ++i) {
#pragma unroll
        for (int j = 0; j < 8; ++j) {
            float v = acc[i][j] + bias[gn + j];
            size_t o = (size_t)(gm + i) * ldc + (gn + j);
            if (MODE == 0) {
                C[o] = v;
            } else if (MODE == 1) {
                C[o] = fourier1p(gn + j, v);
            } else {
                C[o]      = v;
                C[o + Hh] = fourier1p(gn + j, v);
            }
        }
    }
}

__global__ __launch_bounds__(TPB)
void dist_argmin(const float* __restrict__ Z, const float* __restrict__ E,
                 const float* __restrict__ e2, ull* __restrict__ gkey)
{
    __shared__ float As[16][132];
    __shared__ float Bs[16][132];
    __shared__ ull   red[128][16];
    const int t  = threadIdx.x;
    const int bn = blockIdx.x, bm = blockIdx.y;
    const int rowL = t >> 2;
    const int kq   = t & 3;
    const int rm   = (t >> 4) << 3;
    const int rn   = (t & 15) << 3;
    const int Kd = Dd;

    const float* Ab = Z + (size_t)(bm * 128 + rowL) * Kd + kq * 4;
    const float* Bb = E + (size_t)(bn * 128 + rowL) * Kd + kq * 4;
    const size_t strideHalf = (size_t)64 * Kd;

    float acc[8][8];
#pragma unroll
    for (int i = 0; i < 8; ++i)
#pragma unroll
        for (int j = 0; j < 8; ++j) acc[i][j] = 0.f;

    for (int k0 = 0; k0 < Kd; k0 += 16) {
        float4 a0 = *(const float4*)(Ab + k0);
        float4 a1 = *(const float4*)(Ab + strideHalf + k0);
        float4 b0 = *(const float4*)(Bb + k0);
        float4 b1 = *(const float4*)(Bb + strideHalf + k0);
        __syncthreads();
        As[kq*4+0][rowL]    = a0.x; As[kq*4+1][rowL]    = a0.y;
        As[kq*4+2][rowL]    = a0.z; As[kq*4+3][rowL]    = a0.w;
        As[kq*4+0][rowL+64] = a1.x; As[kq*4+1][rowL+64] = a1.y;
        As[kq*4+2][rowL+64] = a1.z; As[kq*4+3][rowL+64] = a1.w;
        Bs[kq*4+0][rowL]    = b0.x; Bs[kq*4+1][rowL]    = b0.y;
        Bs[kq*4+2][rowL]    = b0.z; Bs[kq*4+3][rowL]    = b0.w;
        Bs[kq*4+0][rowL+64] = b1.x; Bs[kq*4+1][rowL+64] = b1.y;
        Bs[kq*4+2][rowL+64] = b1.z; Bs[kq*4+3][rowL+64] = b1.w;
        __syncthreads();
#pragma unroll
        for (int kk = 0; kk < 16; ++kk) {
            float4 av0 = *(const float4*)&As[kk][rm];
            float4 av1 = *(const float4*)&As[kk][rm + 4];
            float4 bv0 = *(const float4*)&Bs[kk][rn];
            float4 bv1 = *(const float4*)&Bs[kk][rn + 4];
            float a[8] = {av0.x, av0.y, av0.z, av0.w, av1.x, av1.y, av1.z, av1.w};
            float b[8] = {bv0.x, bv0.y, bv0.z, bv0.w, bv1.x, bv1.y, bv1.z, bv1.w};
#pragma unroll
            for (int i = 0; i < 8; ++i)
#pragma unroll
                for (int j = 0; j < 8; ++j)
                    acc[i][j] = fmaf(a[i], b[j], acc[i][j]);
        }
    }

    const int gn = bn * 128 + rn;
#pragma unroll
    for (int i = 0; i < 8; ++i) {
        ull best = ~0ull;
#pragma unroll
        for (int j = 0; j < 8; ++j) {
            int gk = gn + j;
            float sc = e2[gk] - 2.0f * acc[i][j];
            unsigned u = __float_as_uint(sc);
            u = (u & 0x80000000u) ? ~u : (u | 0x80000000u);
            ull key = ((ull)u << 32) | (unsigned)gk;
            best = best < key ? best : key;
        }
        red[rm + i][t & 15] = best;
    }
    __syncthreads();
    if (t < 128) {
        ull m = red[t][0];
#pragma unroll
        for (int q = 1; q < 16; ++q) m = m < red[t][q] ? m : red[t][q];
        atomicMin(&gkey[(size_t)bm * 128 + t], m);
    }
}

// ===========================================================================
extern "C" void kernel_launch(void* const* d_in, const int* in_sizes, int n_in,
                              void* d_out, int out_size, void* d_ws, size_t ws_size,
                              hipStream_t stream) {
    const float* x   = (const float*)d_in[0];
    const float* w1  = (const float*)d_in[1];
    const float* b1  = (const float*)d_in[2];
    const float* w2  = (const float*)d_in[3];
    const float* b2  = (const float*)d_in[4];
    const float* w3  = (const float*)d_in[5];
    const float* b3  = (const float*)d_in[6];
    const float* w4  = (const float*)d_in[7];
    const float* b4  = (const float*)d_in[8];
    const float* emb = (const float*)d_in[9];
    float* out = (float*)d_out;

    const size_t MB = 1024 * 1024;

    if (ws_size >= 512 * MB) {
        // ---------------- fast split-fp16 MFMA path ----------------
        // Arena (512 MiB), overlaid by liveness:
        //  R1 @0     (256): hcat planes (GEMM1->GEMM2); then w3/w4/emb planes + e2 + gkey
        //  R2 @256MB (128): w2 planes (->GEMM2); then h3 planes
        //  R3 @384MB (128): x + w1 planes (->GEMM1); then h2 planes
        // Activation planes (x, hcat, h2, h3, z) are fragment-tiled (A-side);
        // weight/emb planes are row-major (B-side, LDS-staged).
        char* W = (char*)d_ws;
        _Float16* hcat_h = (_Float16*)(W);
        _Float16* hcat_l = (_Float16*)(W + 128 * MB);
        _Float16* w3h = (_Float16*)(W);
        _Float16* w3l = (_Float16*)(W + 32 * MB);
        _Float16* w4h = (_Float16*)(W + 64 * MB);
        _Float16* w4l = (_Float16*)(W + 72 * MB);
        _Float16* eh  = (_Float16*)(W + 80 * MB);
        _Float16* el  = (_Float16*)(W + 88 * MB);
        float*    e2b = (float*)   (W + 96 * MB);
        ull*      gkey = (ull*)    (W + 96 * MB + 16 * 1024);
        _Float16* w2h = (_Float16*)(W + 256 * MB);
        _Float16* w2l = (_Float16*)(W + 320 * MB);
        _Float16* h3h = (_Float16*)(W + 256 * MB);
        _Float16* h3l = (_Float16*)(W + 320 * MB);
        _Float16* xh  = (_Float16*)(W + 384 * MB);
        _Float16* xl  = (_Float16*)(W + 400 * MB);
        _Float16* w1h = (_Float16*)(W + 416 * MB);
        _Float16* w1l = (_Float16*)(W + 424 * MB);
        _Float16* h2h = (_Float16*)(W + 384 * MB);
        _Float16* h2l = (_Float16*)(W + 448 * MB);
        _Float16* zh  = (_Float16*)d_out;            // z planes live in d_out
        _Float16* zl  = zh + (size_t)NB * Dd;

        const float WS = 64.0f, IWS = 1.0f / 64.0f;  // weight pre-scale (pow2):
        // keeps lo-plane of sigma=0.02 weights out of fp16 subnormal/FTZ range

        split_f16_frag<<<dim3(1048576 / 256), 256, 0, stream>>>(x, xh, xl, 1048576, Dd);
        split_f16<<<dim3(524288  / 256), 256, 0, stream>>>(w1, w1h, w1l, 524288,  WS);
        split_f16<<<dim3(4194304 / 256), 256, 0, stream>>>(w2, w2h, w2l, 4194304, WS);

        // L1: hcat = [h, fourier(h)], h = x@w1^T + b1
        gemm_split<2><<<dim3(Hh / 256, NB / 128), TPB, 0, stream>>>(
            xh, xl, w1h, w1l, b1, IWS, hcat_h, hcat_l, Dd, 2 * Hh, nullptr, nullptr);
        // L2: h2 = fourier(hcat@w2^T + b2)
        gemm_split<1><<<dim3(Hh / 256, NB / 128), TPB, 0, stream>>>(
            hcat_h, hcat_l, w2h, w2l, b2, IWS, h2h, h2l, 2 * Hh, Hh, nullptr, nullptr);

        // hcat dead -> convert remaining operands into R1
        split_f16<<<dim3(2097152 / 256), 256, 0, stream>>>(w3,  w3h, w3l, 2097152, WS);
        split_f16<<<dim3(524288  / 256), 256, 0, stream>>>(w4,  w4h, w4l, 524288,  WS);
        split_f16<<<dim3(524288  / 256), 256, 0, stream>>>(emb, eh,  el,  524288,  1.0f);
        e2_kernel<<<dim3(Kc), dim3(256), 0, stream>>>(emb, e2b);
        init_gkey<<<dim3(NB / 256), dim3(256), 0, stream>>>(gkey);

        // L3: h3 = fourier(h2@w3^T + b3)
        gemm_split<1><<<dim3(Hh / 256, NB / 128), TPB, 0, stream>>>(
            h2h, h2l, w3h, w3l, b3, IWS, h3h, h3l, Hh, Hh, nullptr, nullptr);
        // L4: z = h3@w4^T + b4
        gemm_split<0><<<dim3(Dd / 256, NB / 128), TPB, 0, stream>>>(
            h3h, h3l, w4h, w4l, b4, IWS, zh, zl, Hh, Dd, nullptr, nullptr);
        // argmin over codes
        gemm_split<3><<<dim3(Kc / 256, NB / 128), TPB, 0, stream>>>(
            zh, zl, eh, el, nullptr, 1.0f, nullptr, nullptr, Dd, 0, e2b, gkey);

        out_kernel<<<dim3(NB), dim3(256), 0, stream>>>(emb, gkey, out);
    } else {
        // ---------------- fallback fp32 path (round-1) ----------------
        float* hcat  = (float*)d_ws;
        float* h2    = hcat + (size_t)NB * 2 * Hh;
        float* e2buf = h2 + (size_t)NB * Hh;
        ull*   gkey  = (ull*)(e2buf + Kc);
        float* h3    = hcat;

        init_gkey<<<dim3((NB + 255) / 256), dim3(256), 0, stream>>>(gkey);
        e2_kernel<<<dim3(Kc), dim3(256), 0, stream>>>(emb, e2buf);
        gemm_tn<2><<<dim3(Hh / 128, NB / 128), TPB, 0, stream>>>(x, w1, b1, hcat, Dd, 2 * Hh);
        gemm_tn<1><<<dim3(Hh / 128, NB / 128), TPB, 0, stream>>>(hcat, w2, b2, h2, 2 * Hh, Hh);
        gemm_tn<1><<<dim3(Hh / 128, NB / 128), TPB, 0, stream>>>(h2, w3, b3, h3, Hh, Hh);
        gemm_tn<0><<<dim3(Dd / 128, NB / 128), TPB, 0, stream>>>(h3, w4, b4, out, Hh, Dd);
        dist_argmin<<<dim3(Kc / 128, NB / 128), TPB, 0, stream>>>(out, emb, e2buf, gkey);
        out_kernel<<<dim3(NB), dim3(256), 0, stream>>>(emb, gkey, out);
    }
}